// Round 1
// baseline (269.298 us; speedup 1.0000x reference)
//
#include <hip/hip_runtime.h>
#include <math.h>

#define KN 20
#define DD 64
#define CATD 128
#define WPB 4   // waves per block

__global__ __launch_bounds__(256, 2) void cnn_kernel(
    const int* __restrict__ user_idxs, const int* __restrict__ item_idxs,
    const int* __restrict__ user_idx_tensor, const float* __restrict__ user_scr_tensor,
    const int* __restrict__ item_idx_tensor, const float* __restrict__ item_scr_tensor,
    const float* __restrict__ user_emb, const float* __restrict__ item_emb,
    const float* __restrict__ w1, const float* __restrict__ b1,
    const float* __restrict__ w2, const float* __restrict__ b2,
    const float* __restrict__ w3, const float* __restrict__ b3,
    float* __restrict__ out, int Bn)
{
    __shared__ float xbuf[WPB][KN][CATD];   // x rows; h1 overwrites cols 64..127
    __shared__ float sbuf[WPB][KN][KN];     // score block (user then item)
    __shared__ float h2buf[WPB][KN][33];    // padded stride 33 -> conflict-free row reads
    __shared__ int   nidx[WPB][KN];

    const int w    = threadIdx.x >> 6;
    const int lane = threadIdx.x & 63;
    int b = blockIdx.x * WPB + w;
    if (b >= Bn) b = Bn - 1;               // duplicate work, avoids barrier divergence

    const int uid = user_idxs[b];
    const int iid = item_idxs[b];

    // ================= user side =================
    if (lane < KN) nidx[w][lane] = user_idx_tensor[uid * KN + lane];
    __syncthreads();

    for (int e = lane; e < KN * KN; e += 64) {
        int k = e / KN, j = e % KN;
        sbuf[w][k][j] = user_scr_tensor[nidx[w][k] * KN + j];
    }
    float emb[KN];
    #pragma unroll
    for (int j = 0; j < KN; ++j)
        emb[j] = user_emb[(long)nidx[w][j] * DD + lane];
    __syncthreads();

    #pragma unroll
    for (int k = 0; k < KN; ++k) {
        float srow[KN];
        #pragma unroll
        for (int q = 0; q < KN / 4; ++q) {
            float4 sv = *(const float4*)&sbuf[w][k][q * 4];
            srow[q*4+0] = sv.x; srow[q*4+1] = sv.y; srow[q*4+2] = sv.z; srow[q*4+3] = sv.w;
        }
        float acc = 0.f;
        #pragma unroll
        for (int j = 0; j < KN; ++j) acc += srow[j] * emb[j];
        xbuf[w][k][lane] = acc;
    }
    __syncthreads();   // sbuf/nidx reads done before item side overwrites

    // ================= item side =================
    if (lane < KN) nidx[w][lane] = item_idx_tensor[iid * KN + lane];
    __syncthreads();

    for (int e = lane; e < KN * KN; e += 64) {
        int k = e / KN, j = e % KN;
        sbuf[w][k][j] = item_scr_tensor[nidx[w][k] * KN + j];
    }
    #pragma unroll
    for (int j = 0; j < KN; ++j)
        emb[j] = item_emb[(long)nidx[w][j] * DD + lane];
    __syncthreads();

    #pragma unroll
    for (int k = 0; k < KN; ++k) {
        float srow[KN];
        #pragma unroll
        for (int q = 0; q < KN / 4; ++q) {
            float4 sv = *(const float4*)&sbuf[w][k][q * 4];
            srow[q*4+0] = sv.x; srow[q*4+1] = sv.y; srow[q*4+2] = sv.z; srow[q*4+3] = sv.w;
        }
        float acc = 0.f;
        #pragma unroll
        for (int j = 0; j < KN; ++j) acc += srow[j] * emb[j];
        xbuf[w][k][DD + lane] = acc;
    }
    __syncthreads();   // x complete

    // ================= MLP layer 1: [20,128]@[128,64], lane = out col =================
    float h1acc[KN];
    #pragma unroll
    for (int k = 0; k < KN; ++k) h1acc[k] = b1[lane];
    #pragma unroll
    for (int ch = 0; ch < 4; ++ch) {
        float wreg[32];
        #pragma unroll
        for (int cc = 0; cc < 32; ++cc)
            wreg[cc] = w1[(ch * 32 + cc) * DD + lane];
        #pragma unroll
        for (int k = 0; k < KN; ++k) {
            #pragma unroll
            for (int q = 0; q < 8; ++q) {
                float4 xv = *(const float4*)&xbuf[w][k][ch * 32 + q * 4];
                h1acc[k] += xv.x * wreg[q*4+0] + xv.y * wreg[q*4+1]
                          + xv.z * wreg[q*4+2] + xv.w * wreg[q*4+3];
            }
        }
    }
    __syncthreads();   // all x reads done before h1 overwrites cols 64..127
    #pragma unroll
    for (int k = 0; k < KN; ++k)
        xbuf[w][k][DD + lane] = fmaxf(h1acc[k], 0.f);
    __syncthreads();

    // ================= MLP layer 2: [20,64]@[64,32], lane&31 = out col =================
    const int o2 = lane & 31;
    float h2acc[KN];
    #pragma unroll
    for (int k = 0; k < KN; ++k) h2acc[k] = b2[o2];
    #pragma unroll
    for (int ch = 0; ch < 2; ++ch) {
        float wreg2[32];
        #pragma unroll
        for (int cc = 0; cc < 32; ++cc)
            wreg2[cc] = w2[(ch * 32 + cc) * 32 + o2];
        #pragma unroll
        for (int k = 0; k < KN; ++k) {
            #pragma unroll
            for (int q = 0; q < 8; ++q) {
                float4 hv = *(const float4*)&xbuf[w][k][DD + ch * 32 + q * 4];
                h2acc[k] += hv.x * wreg2[q*4+0] + hv.y * wreg2[q*4+1]
                          + hv.z * wreg2[q*4+2] + hv.w * wreg2[q*4+3];
            }
        }
    }
    #pragma unroll
    for (int k = 0; k < KN; ++k)
        h2buf[w][k][o2] = fmaxf(h2acc[k], 0.f);   // both half-waves write same value
    __syncthreads();

    // ================= logits + sigmoid + mean =================
    float v = 0.f;
    if (lane < KN) {
        float acc = b3[0];
        #pragma unroll
        for (int c = 0; c < 32; ++c)
            acc += h2buf[w][lane][c] * w3[c];
        v = 1.f / (1.f + __expf(-acc));
    }
    #pragma unroll
    for (int off = 32; off > 0; off >>= 1)
        v += __shfl_xor(v, off);
    if (lane == 0) out[b] = v * (1.f / KN);
}

extern "C" void kernel_launch(void* const* d_in, const int* in_sizes, int n_in,
                              void* d_out, int out_size, void* d_ws, size_t ws_size,
                              hipStream_t stream) {
    const int*   user_idxs       = (const int*)  d_in[0];
    const int*   item_idxs       = (const int*)  d_in[1];
    const int*   user_idx_tensor = (const int*)  d_in[2];
    const float* user_scr_tensor = (const float*)d_in[3];
    const int*   item_idx_tensor = (const int*)  d_in[4];
    const float* item_scr_tensor = (const float*)d_in[5];
    const float* user_emb        = (const float*)d_in[6];
    const float* item_emb        = (const float*)d_in[7];
    const float* w1 = (const float*)d_in[8];
    const float* b1 = (const float*)d_in[9];
    const float* w2 = (const float*)d_in[10];
    const float* b2 = (const float*)d_in[11];
    const float* w3 = (const float*)d_in[12];
    const float* b3 = (const float*)d_in[13];
    float* out = (float*)d_out;

    const int Bn = in_sizes[0];
    const int grid = (Bn + WPB - 1) / WPB;
    cnn_kernel<<<grid, 256, 0, stream>>>(
        user_idxs, item_idxs, user_idx_tensor, user_scr_tensor,
        item_idx_tensor, item_scr_tensor, user_emb, item_emb,
        w1, b1, w2, b2, w3, b3, out, Bn);
}

// Round 2
// 203.193 us; speedup vs baseline: 1.3253x; 1.3253x over previous
//
#include <hip/hip_runtime.h>
#include <hip/hip_bf16.h>
#include <math.h>

#define KN 20
#define DD 64
#define WPB 4
#define NUSERS 100000
#define NITEMS 50000

typedef __hip_bfloat16 bf16;

// ================= precompute Y = emb_table @ W1part (folded layer 1) ==========
// Yu[n][o] = sum_c emb_u[n][c] * w1[c][o]        (c,o in 0..63)
// Yi[n][o] = sum_c emb_i[n][c] * w1[64+c][o]
__global__ __launch_bounds__(256, 4) void precompute_Y(
    const float* __restrict__ emb_u, const float* __restrict__ emb_i,
    const float* __restrict__ w1,
    bf16* __restrict__ Yu, bf16* __restrict__ Yi)
{
    const int lane = threadIdx.x & 63;
    const int gw = (int)((blockIdx.x * blockDim.x + threadIdx.x) >> 6);
    const int NW = (int)((gridDim.x * blockDim.x) >> 6);
    int NWu = (NW * 2) / 3;                 // 100k user rows vs 50k item rows
    if (NWu < 1) NWu = 1;

    if (gw < NWu) {
        float wreg[64];
        #pragma unroll
        for (int c = 0; c < 64; ++c) wreg[c] = w1[c * DD + lane];
        for (int n = gw; n < NUSERS; n += NWu) {
            float e = emb_u[(long)n * DD + lane];
            float a0 = 0.f, a1 = 0.f, a2 = 0.f, a3 = 0.f;
            #pragma unroll
            for (int c = 0; c < 64; c += 4) {
                a0 = fmaf(__shfl(e, c + 0), wreg[c + 0], a0);
                a1 = fmaf(__shfl(e, c + 1), wreg[c + 1], a1);
                a2 = fmaf(__shfl(e, c + 2), wreg[c + 2], a2);
                a3 = fmaf(__shfl(e, c + 3), wreg[c + 3], a3);
            }
            Yu[(long)n * DD + lane] = (bf16)((a0 + a1) + (a2 + a3));
        }
    } else {
        float wreg[64];
        #pragma unroll
        for (int c = 0; c < 64; ++c) wreg[c] = w1[(64 + c) * DD + lane];
        const int NWi = NW - NWu;
        for (int n = gw - NWu; n < NITEMS; n += NWi) {
            float e = emb_i[(long)n * DD + lane];
            float a0 = 0.f, a1 = 0.f, a2 = 0.f, a3 = 0.f;
            #pragma unroll
            for (int c = 0; c < 64; c += 4) {
                a0 = fmaf(__shfl(e, c + 0), wreg[c + 0], a0);
                a1 = fmaf(__shfl(e, c + 1), wreg[c + 1], a1);
                a2 = fmaf(__shfl(e, c + 2), wreg[c + 2], a2);
                a3 = fmaf(__shfl(e, c + 3), wreg[c + 3], a3);
            }
            Yi[(long)n * DD + lane] = (bf16)((a0 + a1) + (a2 + a3));
        }
    }
}

// ================= main fused kernel ==========================================
// h1[k][o] = relu(b1[o] + sum_j su[k][j]*Yu[nu[j]][o] + sum_j si[k][j]*Yi[ni[j]][o])
// h2[k][o2] = relu(b2 + h1[k][:] @ w2[:,o2]);  logit = h2 @ w3 + b3; mean(sigmoid)
__global__ __launch_bounds__(256, 4) void cnn_main(
    const int* __restrict__ user_idxs, const int* __restrict__ item_idxs,
    const int* __restrict__ user_idx_tensor, const float* __restrict__ user_scr_tensor,
    const int* __restrict__ item_idx_tensor, const float* __restrict__ item_scr_tensor,
    const bf16* __restrict__ Yu, const bf16* __restrict__ Yi,
    const float* __restrict__ b1,
    const float* __restrict__ w2, const float* __restrict__ b2,
    const float* __restrict__ w3, const float* __restrict__ b3,
    float* __restrict__ out, int Bn)
{
    __shared__ float sbuf[WPB][2 * KN * KN];   // [0..399] user scores, [400..799] item
    __shared__ float h1buf[WPB][KN][DD];

    const int w    = threadIdx.x >> 6;
    const int lane = threadIdx.x & 63;
    int b = blockIdx.x * WPB + w;
    if (b >= Bn) b = Bn - 1;                   // duplicate work, same value stored

    const int uid = user_idxs[b];
    const int iid = item_idxs[b];

    int nvu = 0, nvi = 0;
    if (lane < KN) {
        nvu = user_idx_tensor[uid * KN + lane];
        nvi = item_idx_tensor[iid * KN + lane];
    }

    // ---- stage both 20x20 score blocks into LDS (gathered rows) ----
    for (int e = lane; e < 2 * KN * KN; e += 64) {
        int eu   = (e >= KN * KN) ? (e - KN * KN) : e;
        int r    = eu / KN;
        int c    = eu - r * KN;
        int rowu = __shfl(nvu, r);
        int rowi = __shfl(nvi, r);
        float s  = (e >= KN * KN) ? item_scr_tensor[rowi * KN + c]
                                  : user_scr_tensor[rowu * KN + c];
        sbuf[w][e] = s;
    }

    // ---- gather user Y rows (bf16, coalesced 128B/row) ----
    float y[KN];
    #pragma unroll
    for (int j = 0; j < KN; ++j) {
        int row = __shfl(nvu, j);
        y[j] = (float)Yu[(long)row * DD + lane];
    }

    float h1acc[KN];
    const float b1v = b1[lane];
    #pragma unroll
    for (int k = 0; k < KN; ++k) h1acc[k] = b1v;

    __syncthreads();   // sbuf ready

    // ---- user score matmul: h1acc[k] += sum_j s[k][j] * yu[j][lane] ----
    #pragma unroll
    for (int k = 0; k < KN; ++k) {
        const float4* sp = (const float4*)&sbuf[w][k * KN];
        float s[KN];
        #pragma unroll
        for (int q = 0; q < KN / 4; ++q) {
            float4 v = sp[q];
            s[4*q] = v.x; s[4*q+1] = v.y; s[4*q+2] = v.z; s[4*q+3] = v.w;
        }
        float a = 0.f;
        #pragma unroll
        for (int j = 0; j < KN; ++j) a = fmaf(s[j], y[j], a);
        h1acc[k] += a;
    }

    // ---- item side (reuse y regs) ----
    #pragma unroll
    for (int j = 0; j < KN; ++j) {
        int row = __shfl(nvi, j);
        y[j] = (float)Yi[(long)row * DD + lane];
    }
    #pragma unroll
    for (int k = 0; k < KN; ++k) {
        const float4* sp = (const float4*)&sbuf[w][KN * KN + k * KN];
        float s[KN];
        #pragma unroll
        for (int q = 0; q < KN / 4; ++q) {
            float4 v = sp[q];
            s[4*q] = v.x; s[4*q+1] = v.y; s[4*q+2] = v.z; s[4*q+3] = v.w;
        }
        float a = 0.f;
        #pragma unroll
        for (int j = 0; j < KN; ++j) a = fmaf(s[j], y[j], a);
        h1acc[k] += a;
    }

    // ---- relu -> h1 to LDS ----
    #pragma unroll
    for (int k = 0; k < KN; ++k)
        h1buf[w][k][lane] = fmaxf(h1acc[k], 0.f);

    __syncthreads();   // h1 ready

    // ---- layer2 (half-wave c-split) + layer3 + sigmoid + mean, all in-reg ----
    const int h = lane >> 5, o = lane & 31;
    float wreg2[32];
    #pragma unroll
    for (int cc = 0; cc < 32; ++cc)
        wreg2[cc] = w2[(h * 32 + cc) * 32 + o];
    const float b2v = b2[o];
    const float w3v = w3[o];
    const float b3v = b3[0];

    float sum = 0.f;
    #pragma unroll
    for (int k = 0; k < KN; ++k) {
        const float4* hp = (const float4*)&h1buf[w][k][h * 32];
        float a = 0.f;
        #pragma unroll
        for (int q = 0; q < 8; ++q) {
            float4 v = hp[q];
            a = fmaf(v.x, wreg2[4*q+0], a);
            a = fmaf(v.y, wreg2[4*q+1], a);
            a = fmaf(v.z, wreg2[4*q+2], a);
            a = fmaf(v.w, wreg2[4*q+3], a);
        }
        float h2 = a + __shfl_xor(a, 32) + b2v;   // combine the two c-halves
        h2 = fmaxf(h2, 0.f);
        float p = h2 * w3v;
        #pragma unroll
        for (int off = 16; off > 0; off >>= 1)
            p += __shfl_xor(p, off);              // reduce over 32 out-cols
        float logit = p + b3v;
        sum += 1.f / (1.f + __expf(-logit));
    }
    if (lane == 0) out[b] = sum * (1.f / KN);
}

extern "C" void kernel_launch(void* const* d_in, const int* in_sizes, int n_in,
                              void* d_out, int out_size, void* d_ws, size_t ws_size,
                              hipStream_t stream) {
    const int*   user_idxs       = (const int*)  d_in[0];
    const int*   item_idxs       = (const int*)  d_in[1];
    const int*   user_idx_tensor = (const int*)  d_in[2];
    const float* user_scr_tensor = (const float*)d_in[3];
    const int*   item_idx_tensor = (const int*)  d_in[4];
    const float* item_scr_tensor = (const float*)d_in[5];
    const float* user_emb        = (const float*)d_in[6];
    const float* item_emb        = (const float*)d_in[7];
    const float* w1 = (const float*)d_in[8];
    const float* b1 = (const float*)d_in[9];
    const float* w2 = (const float*)d_in[10];
    const float* b2 = (const float*)d_in[11];
    const float* w3 = (const float*)d_in[12];
    const float* b3 = (const float*)d_in[13];
    float* out = (float*)d_out;

    const int Bn = in_sizes[0];

    // workspace layout: Yu bf16 [100000][64] then Yi bf16 [50000][64]
    bf16* Yu = (bf16*)d_ws;
    bf16* Yi = Yu + (size_t)NUSERS * DD;

    precompute_Y<<<768, 256, 0, stream>>>(user_emb, item_emb, w1, Yu, Yi);

    const int grid = (Bn + WPB - 1) / WPB;
    cnn_main<<<grid, 256, 0, stream>>>(
        user_idxs, item_idxs, user_idx_tensor, user_scr_tensor,
        item_idx_tensor, item_scr_tensor, Yu, Yi,
        b1, w2, b2, w3, b3, out, Bn);
}

// Round 3
// 122.349 us; speedup vs baseline: 2.2011x; 1.6608x over previous
//
#include <hip/hip_runtime.h>
#include <hip/hip_bf16.h>
#include <math.h>

#define KN 20
#define DD 64
#define WPB 4
#define NUSERS 100000
#define NITEMS 50000
#define NBU 1024   // blocks assigned to user table
#define NBI 512    // blocks assigned to item table

typedef __hip_bfloat16 bf16;

// ================= precompute Y = emb_table @ W1part (folded layer 1) ==========
// Yu[n][o] = sum_c emb_u[n][c] * w1[c][o]        (c,o in 0..63)
// Yi[n][o] = sum_c emb_i[n][c] * w1[64+c][o]
// One wave processes 4 rows per iteration: coalesced float4 load -> wave-private
// LDS stage -> broadcast float4 reads + FMA with W held in 64 VGPRs (lane = o).
__global__ __launch_bounds__(256, 4) void precompute_Y(
    const float* __restrict__ emb_u, const float* __restrict__ emb_i,
    const float* __restrict__ w1,
    bf16* __restrict__ Yu, bf16* __restrict__ Yi)
{
    __shared__ float stage[WPB][256];
    const int w    = threadIdx.x >> 6;
    const int lane = threadIdx.x & 63;

    const bool isU = (int)blockIdx.x < NBU;
    const float* __restrict__ emb  = isU ? emb_u : emb_i;
    bf16* __restrict__       Y     = isU ? Yu : Yi;
    const float* __restrict__ wsrc = isU ? w1 : (w1 + 64 * DD);
    const int ngroups = (isU ? NUSERS : NITEMS) / 4;
    const int bidx    = isU ? (int)blockIdx.x : ((int)blockIdx.x - NBU);
    const int nwaves  = (isU ? NBU : NBI) * WPB;
    const int wid     = bidx * WPB + w;

    float wreg[64];
    #pragma unroll
    for (int c = 0; c < 64; ++c) wreg[c] = wsrc[c * DD + lane];

    for (int g = wid; g < ngroups; g += nwaves) {
        // 4 rows = 256 floats, one float4 per lane, coalesced 1KB
        float4 v = *(const float4*)&emb[(size_t)g * 256 + lane * 4];
        *(float4*)&stage[w][lane * 4] = v;
        // wave-private slot: in-wave RAW through LDS, compiler inserts lgkmcnt
        #pragma unroll
        for (int r = 0; r < 4; ++r) {
            float a0 = 0.f, a1 = 0.f, a2 = 0.f, a3 = 0.f;
            #pragma unroll
            for (int q = 0; q < 16; ++q) {
                float4 e4 = *(const float4*)&stage[w][r * 64 + q * 4];
                a0 = fmaf(e4.x, wreg[q * 4 + 0], a0);
                a1 = fmaf(e4.y, wreg[q * 4 + 1], a1);
                a2 = fmaf(e4.z, wreg[q * 4 + 2], a2);
                a3 = fmaf(e4.w, wreg[q * 4 + 3], a3);
            }
            Y[(size_t)(g * 4 + r) * DD + lane] = (bf16)((a0 + a1) + (a2 + a3));
        }
    }
}

// ================= main fused kernel ==========================================
// h1[k][o] = relu(b1[o] + sum_j su[k][j]*Yu[nu[j]][o] + sum_j si[k][j]*Yi[ni[j]][o])
// h2[k][o2] = relu(b2 + h1[k][:] @ w2[:,o2]);  logit = h2 @ w3 + b3; mean(sigmoid)
__global__ __launch_bounds__(256, 4) void cnn_main(
    const int* __restrict__ user_idxs, const int* __restrict__ item_idxs,
    const int* __restrict__ user_idx_tensor, const float* __restrict__ user_scr_tensor,
    const int* __restrict__ item_idx_tensor, const float* __restrict__ item_scr_tensor,
    const bf16* __restrict__ Yu, const bf16* __restrict__ Yi,
    const float* __restrict__ b1,
    const float* __restrict__ w2, const float* __restrict__ b2,
    const float* __restrict__ w3, const float* __restrict__ b3,
    float* __restrict__ out, int Bn)
{
    __shared__ float sbuf[WPB][2 * KN * KN];   // [0..399] user scores, [400..799] item
    __shared__ float h1buf[WPB][KN][DD];

    const int w    = threadIdx.x >> 6;
    const int lane = threadIdx.x & 63;
    int b = blockIdx.x * WPB + w;
    if (b >= Bn) b = Bn - 1;                   // duplicate work, same value stored

    const int uid = user_idxs[b];
    const int iid = item_idxs[b];

    int nvu = 0, nvi = 0;
    if (lane < KN) {
        nvu = user_idx_tensor[uid * KN + lane];
        nvi = item_idx_tensor[iid * KN + lane];
    }

    // ---- stage both 20x20 score blocks into LDS (gathered rows) ----
    for (int e = lane; e < 2 * KN * KN; e += 64) {
        int eu   = (e >= KN * KN) ? (e - KN * KN) : e;
        int r    = eu / KN;
        int c    = eu - r * KN;
        int rowu = __shfl(nvu, r);
        int rowi = __shfl(nvi, r);
        float s  = (e >= KN * KN) ? item_scr_tensor[rowi * KN + c]
                                  : user_scr_tensor[rowu * KN + c];
        sbuf[w][e] = s;
    }

    // ---- gather user Y rows (bf16, coalesced 128B/row) ----
    float y[KN];
    #pragma unroll
    for (int j = 0; j < KN; ++j) {
        int row = __shfl(nvu, j);
        y[j] = (float)Yu[(long)row * DD + lane];
    }

    float h1acc[KN];
    const float b1v = b1[lane];
    #pragma unroll
    for (int k = 0; k < KN; ++k) h1acc[k] = b1v;

    __syncthreads();   // sbuf ready

    // ---- user score matmul: h1acc[k] += sum_j s[k][j] * yu[j][lane] ----
    #pragma unroll
    for (int k = 0; k < KN; ++k) {
        const float4* sp = (const float4*)&sbuf[w][k * KN];
        float s[KN];
        #pragma unroll
        for (int q = 0; q < KN / 4; ++q) {
            float4 v = sp[q];
            s[4*q] = v.x; s[4*q+1] = v.y; s[4*q+2] = v.z; s[4*q+3] = v.w;
        }
        float a = 0.f;
        #pragma unroll
        for (int j = 0; j < KN; ++j) a = fmaf(s[j], y[j], a);
        h1acc[k] += a;
    }

    // ---- item side (reuse y regs) ----
    #pragma unroll
    for (int j = 0; j < KN; ++j) {
        int row = __shfl(nvi, j);
        y[j] = (float)Yi[(long)row * DD + lane];
    }
    #pragma unroll
    for (int k = 0; k < KN; ++k) {
        const float4* sp = (const float4*)&sbuf[w][KN * KN + k * KN];
        float s[KN];
        #pragma unroll
        for (int q = 0; q < KN / 4; ++q) {
            float4 v = sp[q];
            s[4*q] = v.x; s[4*q+1] = v.y; s[4*q+2] = v.z; s[4*q+3] = v.w;
        }
        float a = 0.f;
        #pragma unroll
        for (int j = 0; j < KN; ++j) a = fmaf(s[j], y[j], a);
        h1acc[k] += a;
    }

    // ---- relu -> h1 to LDS ----
    #pragma unroll
    for (int k = 0; k < KN; ++k)
        h1buf[w][k][lane] = fmaxf(h1acc[k], 0.f);

    __syncthreads();   // h1 ready

    // ---- layer2 (half-wave c-split) + layer3 + sigmoid + mean, all in-reg ----
    const int h = lane >> 5, o = lane & 31;
    float wreg2[32];
    #pragma unroll
    for (int cc = 0; cc < 32; ++cc)
        wreg2[cc] = w2[(h * 32 + cc) * 32 + o];
    const float b2v = b2[o];
    const float w3v = w3[o];
    const float b3v = b3[0];

    float sum = 0.f;
    #pragma unroll
    for (int k = 0; k < KN; ++k) {
        const float4* hp = (const float4*)&h1buf[w][k][h * 32];
        float a = 0.f;
        #pragma unroll
        for (int q = 0; q < 8; ++q) {
            float4 v = hp[q];
            a = fmaf(v.x, wreg2[4*q+0], a);
            a = fmaf(v.y, wreg2[4*q+1], a);
            a = fmaf(v.z, wreg2[4*q+2], a);
            a = fmaf(v.w, wreg2[4*q+3], a);
        }
        float h2 = a + __shfl_xor(a, 32) + b2v;   // combine the two c-halves
        h2 = fmaxf(h2, 0.f);
        float p = h2 * w3v;
        #pragma unroll
        for (int off = 16; off > 0; off >>= 1)
            p += __shfl_xor(p, off);              // reduce over 32 out-cols
        float logit = p + b3v;
        sum += 1.f / (1.f + __expf(-logit));
    }
    if (lane == 0) out[b] = sum * (1.f / KN);
}

extern "C" void kernel_launch(void* const* d_in, const int* in_sizes, int n_in,
                              void* d_out, int out_size, void* d_ws, size_t ws_size,
                              hipStream_t stream) {
    const int*   user_idxs       = (const int*)  d_in[0];
    const int*   item_idxs       = (const int*)  d_in[1];
    const int*   user_idx_tensor = (const int*)  d_in[2];
    const float* user_scr_tensor = (const float*)d_in[3];
    const int*   item_idx_tensor = (const int*)  d_in[4];
    const float* item_scr_tensor = (const float*)d_in[5];
    const float* user_emb        = (const float*)d_in[6];
    const float* item_emb        = (const float*)d_in[7];
    const float* w1 = (const float*)d_in[8];
    const float* b1 = (const float*)d_in[9];
    const float* w2 = (const float*)d_in[10];
    const float* b2 = (const float*)d_in[11];
    const float* w3 = (const float*)d_in[12];
    const float* b3 = (const float*)d_in[13];
    float* out = (float*)d_out;

    const int Bn = in_sizes[0];

    // workspace layout: Yu bf16 [100000][64] then Yi bf16 [50000][64]
    bf16* Yu = (bf16*)d_ws;
    bf16* Yi = Yu + (size_t)NUSERS * DD;

    precompute_Y<<<NBU + NBI, 256, 0, stream>>>(user_emb, item_emb, w1, Yu, Yi);

    const int grid = (Bn + WPB - 1) / WPB;
    cnn_main<<<grid, 256, 0, stream>>>(
        user_idxs, item_idxs, user_idx_tensor, user_scr_tensor,
        item_idx_tensor, item_scr_tensor, Yu, Yi,
        b1, w2, b2, w3, b3, out, Bn);
}